// Round 10
// baseline (145.054 us; speedup 1.0000x reference)
//
#include <hip/hip_runtime.h>

#define PI_D 3.14159265358979323846
#define PI_F 3.14159265358979323846f

// ---- workspace layout (floats) ----
// U01 @ 0        : 1048576   U02 @ 1048576 : 1048576   U12 @ 2097152 : 262144
// V01 @ 2359296  : 524288    V02 @ 2883584 : 262144    V12 @ 3145728 : 131072
// P1p @ 3276800  : 128       P2p @ 3276928 : 64

__device__ inline float rtab_val(int n, int m2, int t) {
  if (t == 0) return 1.0f;
  double th = PI_D * (double)t / (double)n;
  double v = sin(th * (double)(m2 - 1)) / sin(th) + cos(th * (double)m2);
  return (float)(v / (double)m2);  // 1/m2 per axis
}

// Fused front kernel: P partials, V pass, out zeroing.
__global__ __launch_bounds__(256) void k_front(const float* __restrict__ X1,
                                               const float* __restrict__ X2,
                                               float* __restrict__ P1p,
                                               float* __restrict__ P2p,
                                               float* __restrict__ V01,
                                               float* __restrict__ V02,
                                               float* __restrict__ V12,
                                               float* __restrict__ out) {
  int bid = blockIdx.x;
  int t = threadIdx.x;
  if (bid == 448) {
    for (int i = t; i < 5376; i += 256) out[i] = 0.f;
    return;
  }
  if (bid < 192) {
    const float* X; float* P; int lg, nsp, idx0;
    if (bid < 128) { X = X1; P = P1p; lg = 7; nsp = 8; idx0 = bid; }
    else           { X = X2; P = P2p; lg = 6; nsp = 4; idx0 = bid - 128; }
    int ch = idx0 / nsp, split = idx0 % nsp;
    int n = 1 << lg;
    int total = n * n;
    int chunk = total / nsp;
    int b0 = split * chunk;
    const float* x = X + (size_t)ch * total + b0;
    float s = 0.f;
    for (int i = t; i < chunk; i += 256) {
      int idx = b0 + i;
      float v = x[i];
      s += (((idx >> lg) ^ idx) & 1) ? -v : v;
    }
#pragma unroll
    for (int off = 32; off > 0; off >>= 1) s += __shfl_down(s, off, 64);
    __shared__ float red[4];
    if ((t & 63) == 0) red[t >> 6] = s;
    __syncthreads();
    if (t == 0) P[ch * nsp + split] = red[0] + red[1] + red[2] + red[3];
    return;
  }
  // V pass: v[ch][nx][my] = sum_ny x[ch][nx][ny] * R[(my - s*ny) mod n1]
  int vbid = bid - 192;
  const float* X; float* V;
  int n1, n2, s, ch, nxg;
  if (vbid < 128)      { X = X1; V = V01; n1 = 256; n2 = 128; s = 2; ch = vbid >> 3; nxg = (vbid & 7) * 16; }
  else if (vbid < 192) { vbid -= 128; X = X2; V = V02; n1 = 256; n2 = 64; s = 4; ch = vbid >> 2; nxg = (vbid & 3) * 16; }
  else                 { vbid -= 192; X = X2; V = V12; n1 = 128; n2 = 64; s = 2; ch = vbid >> 2; nxg = (vbid & 3) * 16; }
  __shared__ float Rl[256];
  __shared__ float Xs[16 * 128];
  for (int i = t; i < n1; i += 256) Rl[i] = rtab_val(n1, n2, i);
  const float4* xch4 =
      (const float4*)(X + (size_t)ch * n2 * n2 + (size_t)nxg * n2);
  int nx4 = (16 * n2) >> 2;
  for (int i = t; i < nx4; i += 256) ((float4*)Xs)[i] = xch4[i];
  __syncthreads();
  int myq = t & 63;
  int nxq = t >> 6;
  int nmy = n1 >> 6;
  int mask = n1 - 1;
  float acc[4][4];
#pragma unroll
  for (int r = 0; r < 4; ++r)
#pragma unroll
    for (int c = 0; c < 4; ++c) acc[r][c] = 0.f;
  for (int ny = 0; ny < n2; ++ny) {
    float xv[4];
#pragma unroll
    for (int r = 0; r < 4; ++r) xv[r] = Xs[(4 * nxq + r) * n2 + ny];
#pragma unroll
    for (int c = 0; c < 4; ++c) {
      float rv = Rl[(myq + 64 * c - s * ny) & mask];
#pragma unroll
      for (int r = 0; r < 4; ++r) acc[r][c] += xv[r] * rv;
    }
  }
  float* vch = V + (size_t)ch * n2 * n1;
#pragma unroll
  for (int r = 0; r < 4; ++r)
    for (int c = 0; c < nmy; ++c)
      vch[(size_t)(nxg + 4 * nxq + r) * n1 + myq + 64 * c] = acc[r][c];
}

// Pass U (standalone, vectorized): u = conv(R, v) - Nyquist rank-1 term.
__global__ __launch_bounds__(256) void k_U(const float* __restrict__ V01,
                                           const float* __restrict__ V02,
                                           const float* __restrict__ V12,
                                           const float* __restrict__ P1p,
                                           const float* __restrict__ P2p,
                                           float* __restrict__ U01,
                                           float* __restrict__ U02,
                                           float* __restrict__ U12) {
  __shared__ float sRl[256];
  __shared__ float sBuf[4096];
  int u = blockIdx.x;
  int t = threadIdx.x;
  if (u < 512) {
    const float* V; const float* Pp; float* U;
    int n2, s, ch, mxg, nsp; float inv;
    if (u < 256) { V = V01; Pp = P1p; nsp = 8; U = U01; n2 = 128; s = 2; inv = 1.f / (128.f * 128.f); ch = u >> 4; mxg = (u & 15) * 16; }
    else { int w = u - 256; V = V02; Pp = P2p; nsp = 4; U = U02; n2 = 64; s = 4; inv = 1.f / (64.f * 64.f); ch = w >> 4; mxg = (w & 15) * 16; }
    sRl[t] = rtab_val(256, n2, t);
    int cid = t & 63;
    int wv = t >> 6;
    float4 acc[4];
#pragma unroll
    for (int r = 0; r < 4; ++r) acc[r] = make_float4(0.f, 0.f, 0.f, 0.f);
    const float* vch = V + (size_t)ch * n2 * 256;
    for (int nx0 = 0; nx0 < n2; nx0 += 16) {
      __syncthreads();
      const float4* s4 = (const float4*)(vch + (size_t)nx0 * 256);
      for (int i = t; i < 1024; i += 256) ((float4*)sBuf)[i] = s4[i];
      __syncthreads();
#pragma unroll
      for (int k = 0; k < 16; ++k) {
        int nx = nx0 + k;
        float4 vv = *(const float4*)&sBuf[k * 256 + 4 * cid];
        int ib = (mxg + 4 * wv - s * nx) & 255;
        float rv[4];
#pragma unroll
        for (int r = 0; r < 4; ++r) rv[r] = sRl[(ib + r) & 255];
#pragma unroll
        for (int r = 0; r < 4; ++r) {
          acc[r].x += rv[r] * vv.x;
          acc[r].y += rv[r] * vv.y;
          acc[r].z += rv[r] * vv.z;
          acc[r].w += rv[r] * vv.w;
        }
      }
    }
    float Pv = 0.f;
    for (int i = 0; i < nsp; ++i) Pv += Pp[ch * nsp + i];
    float a = PI_F / (float)s;
    int per = 2 * s;
    float smy[4];
#pragma unroll
    for (int j = 0; j < 4; ++j) smy[j] = sinf(a * (float)((4 * cid + j) & (per - 1)));
    float* uch = U + (size_t)ch * 65536;
#pragma unroll
    for (int r = 0; r < 4; ++r) {
      int mx = mxg + 4 * wv + r;
      float q = inv * sinf(a * (float)(mx & (per - 1))) * Pv;
      float4 o = acc[r];
      o.x -= q * smy[0]; o.y -= q * smy[1]; o.z -= q * smy[2]; o.w -= q * smy[3];
      *(float4*)&uch[(size_t)mx * 256 + 4 * cid] = o;
    }
  } else {
    // p12: n1=128, n2=64, s=2
    int w = u - 512;
    int ch = w >> 3, mxg = (w & 7) * 16;
    const float inv = 1.f / (64.f * 64.f);
    if (t < 128) sRl[t] = rtab_val(128, 64, t);
    int cid = t & 31;
    int sub = (t >> 5) & 1;
    int wv = t >> 6;
    float4 acc[2];
    acc[0] = make_float4(0.f, 0.f, 0.f, 0.f);
    acc[1] = make_float4(0.f, 0.f, 0.f, 0.f);
    const float* vch = V12 + (size_t)ch * 64 * 128;
    for (int nx0 = 0; nx0 < 64; nx0 += 16) {
      __syncthreads();
      const float4* s4 = (const float4*)(vch + (size_t)nx0 * 128);
      for (int i = t; i < 512; i += 256) ((float4*)sBuf)[i] = s4[i];
      __syncthreads();
#pragma unroll
      for (int k = 0; k < 16; ++k) {
        int nx = nx0 + k;
        float4 vv = *(const float4*)&sBuf[k * 128 + 4 * cid];
        int ib = (mxg + 4 * wv + 2 * sub - 2 * nx) & 127;
        float r0 = sRl[ib];
        float r1 = sRl[(ib + 1) & 127];
        acc[0].x += r0 * vv.x; acc[0].y += r0 * vv.y;
        acc[0].z += r0 * vv.z; acc[0].w += r0 * vv.w;
        acc[1].x += r1 * vv.x; acc[1].y += r1 * vv.y;
        acc[1].z += r1 * vv.z; acc[1].w += r1 * vv.w;
      }
    }
    float Pv = 0.f;
    for (int i = 0; i < 4; ++i) Pv += P2p[ch * 4 + i];
    const float a = PI_F * 0.5f;
    float smy[4];
#pragma unroll
    for (int j = 0; j < 4; ++j) smy[j] = sinf(a * (float)((4 * cid + j) & 3));
    float* uch = U12 + (size_t)ch * 16384;
#pragma unroll
    for (int r = 0; r < 2; ++r) {
      int mx = mxg + 4 * wv + 2 * sub + r;
      float q = inv * sinf(a * (float)(mx & 3)) * Pv;
      float4 o = acc[r];
      o.x -= q * smy[0]; o.y -= q * smy[1]; o.z -= q * smy[2]; o.w -= q * smy[3];
      *(float4*)&uch[(size_t)mx * 128 + 4 * cid] = o;
    }
  }
}

// 7-point correlation, lane-specialized: lane t&7 owns l1, t>>3 owns an
// 8-column group. acc = 7 regs/lane; reduction = 3 shuffles (stride-8 tree).
// All 6 groups, 8-row chunks -> grid 2176.
__global__ __launch_bounds__(256) void k_corr(const float* __restrict__ X0,
                                              const float* __restrict__ X1,
                                              const float* __restrict__ X2,
                                              const float* __restrict__ U01,
                                              const float* __restrict__ U02,
                                              const float* __restrict__ U12,
                                              float* __restrict__ out) {
  int u = blockIdx.x;
  const float* A1b; const float* A2b; int loc, lgn1, base;
  if (u < 512)       { loc = u;        A1b = X0; A2b = X0;  lgn1 = 8; base = 0;   }
  else if (u < 1024) { loc = u - 512;  A1b = X0; A2b = U01; lgn1 = 8; base = 64;  }
  else if (u < 1536) { loc = u - 1024; A1b = X0; A2b = U02; lgn1 = 8; base = 128; }
  else if (u < 1792) { loc = u - 1536; A1b = X1; A2b = X1;  lgn1 = 7; base = 192; }
  else if (u < 2048) { loc = u - 1792; A1b = X1; A2b = U12; lgn1 = 7; base = 256; }
  else               { loc = u - 2048; A1b = X2; A2b = X2;  lgn1 = 6; base = 320; }
  int n1 = 1 << lgn1;
  int mask = n1 - 1;
  int n1sq = n1 * n1;
  int lgc = lgn1 - 3;  // #chunks of 8 rows: 32/16/8
  int chunk = loc & ((1 << lgc) - 1);
  int bl2 = loc >> lgc;
  int b = bl2 >> 3, l2 = bl2 & 7;
  int t = threadIdx.x;
  int l1 = t & 7;
  int lgg = lgn1 - 3;                 // #col groups: 32/16/8
  int g = (t >> 3) & ((1 << lgg) - 1);
  int rid = t >> (3 + lgg);           // rows in flight: 1/2/4
  int rif = 256 >> (3 + lgg);
  int ty = g * 8;
  int tym = (ty - 4) & mask;          // wraps only at g=0
  int typ = ty + 4;                   // never wraps (ty <= n1-8)
  const float* A1 = A1b + (size_t)(b * 8 + l1) * n1sq;
  const float* A2 = A2b + (size_t)(b * 8 + l2) * n1sq;
  float acc[7] = {0.f, 0.f, 0.f, 0.f, 0.f, 0.f, 0.f};
  for (int rr = 0; rr < 8; rr += rif) {
    int row = chunk * 8 + rr + rid;
    const float* r0 = A2 + (size_t)row * n1;
    const float* r1 = A2 + (size_t)((row - 1) & mask) * n1;
    const float* r2 = A2 + (size_t)((row - 2) & mask) * n1;
    const float* r3 = A2 + (size_t)((row + 1) & mask) * n1;
    const float* rA = A1 + (size_t)row * n1;
    float4 xv0 = *(const float4*)(rA + ty);
    float4 xv1 = *(const float4*)(rA + typ);
    float4 a0 = *(const float4*)(r0 + tym);
    float4 b0 = *(const float4*)(r0 + ty);
    float4 c0 = *(const float4*)(r0 + typ);
    float4 a1 = *(const float4*)(r1 + tym);
    float4 b1 = *(const float4*)(r1 + ty);
    float4 c1 = *(const float4*)(r1 + typ);
    float4 b2 = *(const float4*)(r2 + ty);
    float4 c2 = *(const float4*)(r2 + typ);
    float4 a3 = *(const float4*)(r3 + tym);
    float4 b3 = *(const float4*)(r3 + ty);
    float4 c3 = *(const float4*)(r3 + typ);
    acc[0] += xv0.x * b0.x + xv0.y * b0.y + xv0.z * b0.z + xv0.w * b0.w
            + xv1.x * c0.x + xv1.y * c0.y + xv1.z * c0.z + xv1.w * c0.w;  // (0,0)
    acc[1] += xv0.x * a0.w + xv0.y * b0.x + xv0.z * b0.y + xv0.w * b0.z
            + xv1.x * b0.w + xv1.y * c0.x + xv1.z * c0.y + xv1.w * c0.z;  // (0,1)
    acc[2] += xv0.x * a0.z + xv0.y * a0.w + xv0.z * b0.x + xv0.w * b0.y
            + xv1.x * b0.z + xv1.y * b0.w + xv1.z * c0.x + xv1.w * c0.y;  // (0,2)
    acc[3] += xv0.x * b1.x + xv0.y * b1.y + xv0.z * b1.z + xv0.w * b1.w
            + xv1.x * c1.x + xv1.y * c1.y + xv1.z * c1.z + xv1.w * c1.w;  // (1,0)
    acc[4] += xv0.x * a1.w + xv0.y * b1.x + xv0.z * b1.y + xv0.w * b1.z
            + xv1.x * b1.w + xv1.y * c1.x + xv1.z * c1.y + xv1.w * c1.z;  // (1,1)
    acc[5] += xv0.x * b2.x + xv0.y * b2.y + xv0.z * b2.z + xv0.w * b2.w
            + xv1.x * c2.x + xv1.y * c2.y + xv1.z * c2.z + xv1.w * c2.w;  // (2,0)
    acc[6] += xv0.x * a3.w + xv0.y * b3.x + xv0.z * b3.y + xv0.w * b3.z
            + xv1.x * b3.w + xv1.y * c3.x + xv1.z * c3.y + xv1.w * c3.z;  // (-1,1)
  }
  // 3-level stride-8 shuffle tree: lanes 0..7 end with full wave sums for l1=lane
  __shared__ float red[4][56];
  int lane = t & 63;
  int wv = t >> 6;
#pragma unroll
  for (int p = 0; p < 7; ++p) {
    float v = acc[p];
    v += __shfl_down(v, 32, 64);
    v += __shfl_down(v, 16, 64);
    v += __shfl_down(v, 8, 64);
    if (lane < 8) red[wv][lane * 7 + p] = v;
  }
  __syncthreads();
  if (t < 56) {
    float v = red[0][t] + red[1][t] + red[2][t] + red[3][t];
    int l1o = t / 7, p = t % 7;
    atomicAdd(&out[((size_t)b * 384 + base + l1o * 8 + l2) * 7 + p], v);
  }
}

extern "C" void kernel_launch(void* const* d_in, const int* in_sizes, int n_in,
                              void* d_out, int out_size, void* d_ws, size_t ws_size,
                              hipStream_t stream) {
  const float* X0 = (const float*)d_in[0];  // [2,8,256,256]
  const float* X1 = (const float*)d_in[1];  // [2,8,128,128]
  const float* X2 = (const float*)d_in[2];  // [2,8,64,64]
  float* out = (float*)d_out;               // [2,384,7]
  float* ws = (float*)d_ws;

  float* U01 = ws;
  float* U02 = ws + 1048576;
  float* U12 = ws + 2097152;
  float* V01 = ws + 2359296;
  float* V02 = ws + 2883584;
  float* V12 = ws + 3145728;
  float* P1p = ws + 3276800;
  float* P2p = ws + 3276928;

  k_front<<<449, 256, 0, stream>>>(X1, X2, P1p, P2p, V01, V02, V12, out);
  k_U<<<640, 256, 0, stream>>>(V01, V02, V12, P1p, P2p, U01, U02, U12);
  k_corr<<<2176, 256, 0, stream>>>(X0, X1, X2, U01, U02, U12, out);
}

// Round 11
// 125.459 us; speedup vs baseline: 1.1562x; 1.1562x over previous
//
#include <hip/hip_runtime.h>

#define PI_D 3.14159265358979323846
#define PI_F 3.14159265358979323846f

// ---- workspace layout (floats) ----
// U01 @ 0        : 1048576   U02 @ 1048576 : 1048576   U12 @ 2097152 : 262144
// V01 @ 2359296  : 524288    V02 @ 2883584 : 262144    V12 @ 3145728 : 131072
// P1p @ 3276800  : 128       P2p @ 3276928 : 64

__device__ inline float rtab_val(int n, int m2, int t) {
  if (t == 0) return 1.0f;
  double th = PI_D * (double)t / (double)n;
  double v = sin(th * (double)(m2 - 1)) / sin(th) + cos(th * (double)m2);
  return (float)(v / (double)m2);  // 1/m2 per axis
}

// Fused front kernel: P partials, V pass, out zeroing.
__global__ __launch_bounds__(256) void k_front(const float* __restrict__ X1,
                                               const float* __restrict__ X2,
                                               float* __restrict__ P1p,
                                               float* __restrict__ P2p,
                                               float* __restrict__ V01,
                                               float* __restrict__ V02,
                                               float* __restrict__ V12,
                                               float* __restrict__ out) {
  int bid = blockIdx.x;
  int t = threadIdx.x;
  if (bid == 448) {
    for (int i = t; i < 5376; i += 256) out[i] = 0.f;
    return;
  }
  if (bid < 192) {
    const float* X; float* P; int lg, nsp, idx0;
    if (bid < 128) { X = X1; P = P1p; lg = 7; nsp = 8; idx0 = bid; }
    else           { X = X2; P = P2p; lg = 6; nsp = 4; idx0 = bid - 128; }
    int ch = idx0 / nsp, split = idx0 % nsp;
    int n = 1 << lg;
    int total = n * n;
    int chunk = total / nsp;
    int b0 = split * chunk;
    const float* x = X + (size_t)ch * total + b0;
    float s = 0.f;
    for (int i = t; i < chunk; i += 256) {
      int idx = b0 + i;
      float v = x[i];
      s += (((idx >> lg) ^ idx) & 1) ? -v : v;
    }
#pragma unroll
    for (int off = 32; off > 0; off >>= 1) s += __shfl_down(s, off, 64);
    __shared__ float red[4];
    if ((t & 63) == 0) red[t >> 6] = s;
    __syncthreads();
    if (t == 0) P[ch * nsp + split] = red[0] + red[1] + red[2] + red[3];
    return;
  }
  // V pass: v[ch][nx][my] = sum_ny x[ch][nx][ny] * R[(my - s*ny) mod n1]
  int vbid = bid - 192;
  const float* X; float* V;
  int n1, n2, s, ch, nxg;
  if (vbid < 128)      { X = X1; V = V01; n1 = 256; n2 = 128; s = 2; ch = vbid >> 3; nxg = (vbid & 7) * 16; }
  else if (vbid < 192) { vbid -= 128; X = X2; V = V02; n1 = 256; n2 = 64; s = 4; ch = vbid >> 2; nxg = (vbid & 3) * 16; }
  else                 { vbid -= 192; X = X2; V = V12; n1 = 128; n2 = 64; s = 2; ch = vbid >> 2; nxg = (vbid & 3) * 16; }
  __shared__ float Rl[256];
  __shared__ float Xs[16 * 128];
  for (int i = t; i < n1; i += 256) Rl[i] = rtab_val(n1, n2, i);
  const float4* xch4 =
      (const float4*)(X + (size_t)ch * n2 * n2 + (size_t)nxg * n2);
  int nx4 = (16 * n2) >> 2;
  for (int i = t; i < nx4; i += 256) ((float4*)Xs)[i] = xch4[i];
  __syncthreads();
  int myq = t & 63;
  int nxq = t >> 6;
  int nmy = n1 >> 6;
  int mask = n1 - 1;
  float acc[4][4];
#pragma unroll
  for (int r = 0; r < 4; ++r)
#pragma unroll
    for (int c = 0; c < 4; ++c) acc[r][c] = 0.f;
  for (int ny = 0; ny < n2; ++ny) {
    float xv[4];
#pragma unroll
    for (int r = 0; r < 4; ++r) xv[r] = Xs[(4 * nxq + r) * n2 + ny];
#pragma unroll
    for (int c = 0; c < 4; ++c) {
      float rv = Rl[(myq + 64 * c - s * ny) & mask];
#pragma unroll
      for (int r = 0; r < 4; ++r) acc[r][c] += xv[r] * rv;
    }
  }
  float* vch = V + (size_t)ch * n2 * n1;
#pragma unroll
  for (int r = 0; r < 4; ++r)
    for (int c = 0; c < nmy; ++c)
      vch[(size_t)(nxg + 4 * nxq + r) * n1 + myq + 64 * c] = acc[r][c];
}

// Pass U (standalone, vectorized): u = conv(R, v) - Nyquist rank-1 term.
__global__ __launch_bounds__(256) void k_U(const float* __restrict__ V01,
                                           const float* __restrict__ V02,
                                           const float* __restrict__ V12,
                                           const float* __restrict__ P1p,
                                           const float* __restrict__ P2p,
                                           float* __restrict__ U01,
                                           float* __restrict__ U02,
                                           float* __restrict__ U12) {
  __shared__ float sRl[256];
  __shared__ float sBuf[4096];
  int u = blockIdx.x;
  int t = threadIdx.x;
  if (u < 512) {
    const float* V; const float* Pp; float* U;
    int n2, s, ch, mxg, nsp; float inv;
    if (u < 256) { V = V01; Pp = P1p; nsp = 8; U = U01; n2 = 128; s = 2; inv = 1.f / (128.f * 128.f); ch = u >> 4; mxg = (u & 15) * 16; }
    else { int w = u - 256; V = V02; Pp = P2p; nsp = 4; U = U02; n2 = 64; s = 4; inv = 1.f / (64.f * 64.f); ch = w >> 4; mxg = (w & 15) * 16; }
    sRl[t] = rtab_val(256, n2, t);
    int cid = t & 63;
    int wv = t >> 6;
    float4 acc[4];
#pragma unroll
    for (int r = 0; r < 4; ++r) acc[r] = make_float4(0.f, 0.f, 0.f, 0.f);
    const float* vch = V + (size_t)ch * n2 * 256;
    for (int nx0 = 0; nx0 < n2; nx0 += 16) {
      __syncthreads();
      const float4* s4 = (const float4*)(vch + (size_t)nx0 * 256);
      for (int i = t; i < 1024; i += 256) ((float4*)sBuf)[i] = s4[i];
      __syncthreads();
#pragma unroll
      for (int k = 0; k < 16; ++k) {
        int nx = nx0 + k;
        float4 vv = *(const float4*)&sBuf[k * 256 + 4 * cid];
        int ib = (mxg + 4 * wv - s * nx) & 255;
        float rv[4];
#pragma unroll
        for (int r = 0; r < 4; ++r) rv[r] = sRl[(ib + r) & 255];
#pragma unroll
        for (int r = 0; r < 4; ++r) {
          acc[r].x += rv[r] * vv.x;
          acc[r].y += rv[r] * vv.y;
          acc[r].z += rv[r] * vv.z;
          acc[r].w += rv[r] * vv.w;
        }
      }
    }
    float Pv = 0.f;
    for (int i = 0; i < nsp; ++i) Pv += Pp[ch * nsp + i];
    float a = PI_F / (float)s;
    int per = 2 * s;
    float smy[4];
#pragma unroll
    for (int j = 0; j < 4; ++j) smy[j] = sinf(a * (float)((4 * cid + j) & (per - 1)));
    float* uch = U + (size_t)ch * 65536;
#pragma unroll
    for (int r = 0; r < 4; ++r) {
      int mx = mxg + 4 * wv + r;
      float q = inv * sinf(a * (float)(mx & (per - 1))) * Pv;
      float4 o = acc[r];
      o.x -= q * smy[0]; o.y -= q * smy[1]; o.z -= q * smy[2]; o.w -= q * smy[3];
      *(float4*)&uch[(size_t)mx * 256 + 4 * cid] = o;
    }
  } else {
    // p12: n1=128, n2=64, s=2
    int w = u - 512;
    int ch = w >> 3, mxg = (w & 7) * 16;
    const float inv = 1.f / (64.f * 64.f);
    if (t < 128) sRl[t] = rtab_val(128, 64, t);
    int cid = t & 31;
    int sub = (t >> 5) & 1;
    int wv = t >> 6;
    float4 acc[2];
    acc[0] = make_float4(0.f, 0.f, 0.f, 0.f);
    acc[1] = make_float4(0.f, 0.f, 0.f, 0.f);
    const float* vch = V12 + (size_t)ch * 64 * 128;
    for (int nx0 = 0; nx0 < 64; nx0 += 16) {
      __syncthreads();
      const float4* s4 = (const float4*)(vch + (size_t)nx0 * 128);
      for (int i = t; i < 512; i += 256) ((float4*)sBuf)[i] = s4[i];
      __syncthreads();
#pragma unroll
      for (int k = 0; k < 16; ++k) {
        int nx = nx0 + k;
        float4 vv = *(const float4*)&sBuf[k * 128 + 4 * cid];
        int ib = (mxg + 4 * wv + 2 * sub - 2 * nx) & 127;
        float r0 = sRl[ib];
        float r1 = sRl[(ib + 1) & 127];
        acc[0].x += r0 * vv.x; acc[0].y += r0 * vv.y;
        acc[0].z += r0 * vv.z; acc[0].w += r0 * vv.w;
        acc[1].x += r1 * vv.x; acc[1].y += r1 * vv.y;
        acc[1].z += r1 * vv.z; acc[1].w += r1 * vv.w;
      }
    }
    float Pv = 0.f;
    for (int i = 0; i < 4; ++i) Pv += P2p[ch * 4 + i];
    const float a = PI_F * 0.5f;
    float smy[4];
#pragma unroll
    for (int j = 0; j < 4; ++j) smy[j] = sinf(a * (float)((4 * cid + j) & 3));
    float* uch = U12 + (size_t)ch * 16384;
#pragma unroll
    for (int r = 0; r < 2; ++r) {
      int mx = mxg + 4 * wv + 2 * sub + r;
      float q = inv * sinf(a * (float)(mx & 3)) * Pv;
      float4 o = acc[r];
      o.x -= q * smy[0]; o.y -= q * smy[1]; o.z -= q * smy[2]; o.w -= q * smy[3];
      *(float4*)&uch[(size_t)mx * 128 + 4 * cid] = o;
    }
  }
}

// 7-point correlation: acc[8][7] per lane (A2 shifts reused over 8 l1),
// 16-row chunks -> 1088 blocks. Cheap epilogue: 2-shfl + LDS transpose
// (stride 60 floats: 2-way bank alias max = free).
__global__ __launch_bounds__(256) void k_corr(const float* __restrict__ X0,
                                              const float* __restrict__ X1,
                                              const float* __restrict__ X2,
                                              const float* __restrict__ U01,
                                              const float* __restrict__ U02,
                                              const float* __restrict__ U12,
                                              float* __restrict__ out) {
  __shared__ float smem[64 * 60];  // 15 KB
  int u = blockIdx.x;
  const float* A1b; const float* A2b; int loc, lgn1, base, lgc;
  if (u < 768) {
    int grp = u >> 8;  // 0,1,2
    loc = u & 255;
    lgn1 = 8; lgc = 4;  // 16 chunks of 16 rows
    if (grp == 0)      { A1b = X0; A2b = X0;  base = 0;   }
    else if (grp == 1) { A1b = X0; A2b = U01; base = 64;  }
    else               { A1b = X0; A2b = U02; base = 128; }
  } else if (u < 1024) {
    int w = u - 768;
    int grp = w >> 7;  // 0,1
    loc = w & 127;
    lgn1 = 7; lgc = 3;  // 8 chunks
    if (grp == 0) { A1b = X1; A2b = X1;  base = 192; }
    else          { A1b = X1; A2b = U12; base = 256; }
  } else {
    loc = u - 1024;
    lgn1 = 6; lgc = 2;  // 4 chunks
    A1b = X2; A2b = X2; base = 320;
  }
  int n1 = 1 << lgn1;
  int mask = n1 - 1;
  int n1sq = n1 * n1;
  int chunk = loc & ((1 << lgc) - 1);
  int bl2 = loc >> lgc;
  int b = bl2 >> 3, l2 = bl2 & 7;
  const float* A1 = A1b + (size_t)(b * 8) * n1sq;
  const float* A2 = A2b + (size_t)(b * 8 + l2) * n1sq;
  int t = threadIdx.x;
  int lgtpr = lgn1 - 2;    // threads per row: 64/32/16
  int tpr = 1 << lgtpr;
  int rif = 256 >> lgtpr;  // rows in flight: 4/8/16
  int rid = t >> lgtpr;
  int cid = t & (tpr - 1);
  int ty = cid * 4;
  int tym = (ty - 4) & mask;
  float acc[8][7];
#pragma unroll
  for (int l1 = 0; l1 < 8; ++l1)
#pragma unroll
    for (int p = 0; p < 7; ++p) acc[l1][p] = 0.f;
  for (int rr = 0; rr < 16; rr += rif) {
    int row = chunk * 16 + rr + rid;
    const float* r0 = A2 + (size_t)row * n1;
    const float* r1 = A2 + (size_t)((row - 1) & mask) * n1;
    const float* r2 = A2 + (size_t)((row - 2) & mask) * n1;
    const float* r3 = A2 + (size_t)((row + 1) & mask) * n1;
    float4 a0 = *(const float4*)(r0 + tym);
    float4 b0 = *(const float4*)(r0 + ty);
    float4 a1 = *(const float4*)(r1 + tym);
    float4 b1 = *(const float4*)(r1 + ty);
    float4 b2 = *(const float4*)(r2 + ty);
    float4 a3 = *(const float4*)(r3 + tym);
    float4 b3 = *(const float4*)(r3 + ty);
    const float* rA = A1 + (size_t)row * n1 + ty;
#pragma unroll
    for (int l1 = 0; l1 < 8; ++l1) {
      float4 xv = *(const float4*)(rA + (size_t)l1 * n1sq);
      acc[l1][0] += xv.x * b0.x + xv.y * b0.y + xv.z * b0.z + xv.w * b0.w;  // (0,0)
      acc[l1][1] += xv.x * a0.w + xv.y * b0.x + xv.z * b0.y + xv.w * b0.z;  // (0,1)
      acc[l1][2] += xv.x * a0.z + xv.y * a0.w + xv.z * b0.x + xv.w * b0.y;  // (0,2)
      acc[l1][3] += xv.x * b1.x + xv.y * b1.y + xv.z * b1.z + xv.w * b1.w;  // (1,0)
      acc[l1][4] += xv.x * a1.w + xv.y * b1.x + xv.z * b1.y + xv.w * b1.z;  // (1,1)
      acc[l1][5] += xv.x * b2.x + xv.y * b2.y + xv.z * b2.z + xv.w * b2.w;  // (2,0)
      acc[l1][6] += xv.x * a3.w + xv.y * b3.x + xv.z * b3.y + xv.w * b3.z;  // (-1,1)
    }
  }
  // ---- epilogue ----
  int lane = t & 63;
  int wv = t >> 6;
  float* af = &acc[0][0];
  // fold 64 -> 16 lanes
#pragma unroll
  for (int j = 0; j < 56; ++j) {
    float v = af[j];
    v += __shfl_down(v, 32, 64);
    v += __shfl_down(v, 16, 64);
    af[j] = v;
  }
  if (lane < 16) {
    float* row = smem + (wv * 16 + lane) * 60;
#pragma unroll
    for (int j = 0; j < 14; ++j)
      *(float4*)&row[4 * j] =
          make_float4(af[4 * j], af[4 * j + 1], af[4 * j + 2], af[4 * j + 3]);
  }
  __syncthreads();
  if (t < 224) {
    int v = t >> 2, q = t & 3;
    float s = 0.f;
#pragma unroll
    for (int i = 0; i < 16; ++i) s += smem[(q * 16 + i) * 60 + v];
    s += __shfl_down(s, 2, 64);
    s += __shfl_down(s, 1, 64);
    if (q == 0) {
      int l1 = v / 7, p = v % 7;
      atomicAdd(&out[((size_t)b * 384 + base + l1 * 8 + l2) * 7 + p], s);
    }
  }
}

extern "C" void kernel_launch(void* const* d_in, const int* in_sizes, int n_in,
                              void* d_out, int out_size, void* d_ws, size_t ws_size,
                              hipStream_t stream) {
  const float* X0 = (const float*)d_in[0];  // [2,8,256,256]
  const float* X1 = (const float*)d_in[1];  // [2,8,128,128]
  const float* X2 = (const float*)d_in[2];  // [2,8,64,64]
  float* out = (float*)d_out;               // [2,384,7]
  float* ws = (float*)d_ws;

  float* U01 = ws;
  float* U02 = ws + 1048576;
  float* U12 = ws + 2097152;
  float* V01 = ws + 2359296;
  float* V02 = ws + 2883584;
  float* V12 = ws + 3145728;
  float* P1p = ws + 3276800;
  float* P2p = ws + 3276928;

  k_front<<<449, 256, 0, stream>>>(X1, X2, P1p, P2p, V01, V02, V12, out);
  k_U<<<640, 256, 0, stream>>>(V01, V02, V12, P1p, P2p, U01, U02, U12);
  k_corr<<<1088, 256, 0, stream>>>(X0, X1, X2, U01, U02, U12, out);
}

// Round 12
// 111.548 us; speedup vs baseline: 1.3004x; 1.1247x over previous
//
#include <hip/hip_runtime.h>

#define PI_D 3.14159265358979323846
#define PI_F 3.14159265358979323846f

// ---- workspace layout (floats) ----
// V01 @ 2359296  : 524288    V02 @ 2883584 : 262144    V12 @ 3145728 : 131072
// P1p @ 3276800  : 128       P2p @ 3276928 : 64        (U buffers no longer used)

__device__ inline float rtab_val(int n, int m2, int t) {
  if (t == 0) return 1.0f;
  double th = PI_D * (double)t / (double)n;
  double v = sin(th * (double)(m2 - 1)) / sin(th) + cos(th * (double)m2);
  return (float)(v / (double)m2);  // 1/m2 per axis
}

// Fused front kernel: P partials, V pass, out zeroing. (proven R11 code)
__global__ __launch_bounds__(256) void k_front(const float* __restrict__ X1,
                                               const float* __restrict__ X2,
                                               float* __restrict__ P1p,
                                               float* __restrict__ P2p,
                                               float* __restrict__ V01,
                                               float* __restrict__ V02,
                                               float* __restrict__ V12,
                                               float* __restrict__ out) {
  int bid = blockIdx.x;
  int t = threadIdx.x;
  if (bid == 448) {
    for (int i = t; i < 5376; i += 256) out[i] = 0.f;
    return;
  }
  if (bid < 192) {
    const float* X; float* P; int lg, nsp, idx0;
    if (bid < 128) { X = X1; P = P1p; lg = 7; nsp = 8; idx0 = bid; }
    else           { X = X2; P = P2p; lg = 6; nsp = 4; idx0 = bid - 128; }
    int ch = idx0 / nsp, split = idx0 % nsp;
    int n = 1 << lg;
    int total = n * n;
    int chunk = total / nsp;
    int b0 = split * chunk;
    const float* x = X + (size_t)ch * total + b0;
    float s = 0.f;
    for (int i = t; i < chunk; i += 256) {
      int idx = b0 + i;
      float v = x[i];
      s += (((idx >> lg) ^ idx) & 1) ? -v : v;
    }
#pragma unroll
    for (int off = 32; off > 0; off >>= 1) s += __shfl_down(s, off, 64);
    __shared__ float red[4];
    if ((t & 63) == 0) red[t >> 6] = s;
    __syncthreads();
    if (t == 0) P[ch * nsp + split] = red[0] + red[1] + red[2] + red[3];
    return;
  }
  // V pass: v[ch][nx][my] = sum_ny x[ch][nx][ny] * R[(my - s*ny) mod n1]
  int vbid = bid - 192;
  const float* X; float* V;
  int n1, n2, s, ch, nxg;
  if (vbid < 128)      { X = X1; V = V01; n1 = 256; n2 = 128; s = 2; ch = vbid >> 3; nxg = (vbid & 7) * 16; }
  else if (vbid < 192) { vbid -= 128; X = X2; V = V02; n1 = 256; n2 = 64; s = 4; ch = vbid >> 2; nxg = (vbid & 3) * 16; }
  else                 { vbid -= 192; X = X2; V = V12; n1 = 128; n2 = 64; s = 2; ch = vbid >> 2; nxg = (vbid & 3) * 16; }
  __shared__ float Rl[256];
  __shared__ float Xs[16 * 128];
  for (int i = t; i < n1; i += 256) Rl[i] = rtab_val(n1, n2, i);
  const float4* xch4 =
      (const float4*)(X + (size_t)ch * n2 * n2 + (size_t)nxg * n2);
  int nx4 = (16 * n2) >> 2;
  for (int i = t; i < nx4; i += 256) ((float4*)Xs)[i] = xch4[i];
  __syncthreads();
  int myq = t & 63;
  int nxq = t >> 6;
  int nmy = n1 >> 6;
  int mask = n1 - 1;
  float acc[4][4];
#pragma unroll
  for (int r = 0; r < 4; ++r)
#pragma unroll
    for (int c = 0; c < 4; ++c) acc[r][c] = 0.f;
  for (int ny = 0; ny < n2; ++ny) {
    float xv[4];
#pragma unroll
    for (int r = 0; r < 4; ++r) xv[r] = Xs[(4 * nxq + r) * n2 + ny];
#pragma unroll
    for (int c = 0; c < 4; ++c) {
      float rv = Rl[(myq + 64 * c - s * ny) & mask];
#pragma unroll
      for (int r = 0; r < 4; ++r) acc[r][c] += xv[r] * rv;
    }
  }
  float* vch = V + (size_t)ch * n2 * n1;
#pragma unroll
  for (int r = 0; r < 4; ++r)
    for (int c = 0; c < nmy; ++c)
      vch[(size_t)(nxg + 4 * nxq + r) * n1 + myq + 64 * c] = acc[r][c];
}

// k_main: u<640 fused U(LDS)+corr for upsampled pairs; u in [640,1088) self-corr.
__global__ __launch_bounds__(256) void k_main(const float* __restrict__ X0,
                                              const float* __restrict__ X1,
                                              const float* __restrict__ X2,
                                              const float* __restrict__ V01,
                                              const float* __restrict__ V02,
                                              const float* __restrict__ V12,
                                              const float* __restrict__ P1p,
                                              const float* __restrict__ P2p,
                                              float* __restrict__ out) {
  __shared__ float smem[9472];    // 37 KB
  float* sRl = smem;              // 256
  float* Us = smem + 256;         // 19*256 = 4864
  float* eBuf = smem + 5120;      // 4096 (V staging / epilogue)
  int u = blockIdx.x;
  int t = threadIdx.x;
  int lane = t & 63;
  int wv = t >> 6;

  float accC[8][7];
#pragma unroll
  for (int i = 0; i < 8; ++i)
#pragma unroll
    for (int p = 0; p < 7; ++p) accC[i][p] = 0.f;

  int base, b, l2;

  if (u < 640) {
    // ================= fused U + corr =================
    const float* V; const float* Pp; const float* A1b;
    int n1, n2, s, ch, chunk, nsp, lgn1; float inv;
    if (u < 256)      { V = V01; Pp = P1p; nsp = 8; A1b = X0; n1 = 256; n2 = 128; s = 2; inv = 1.f / (128.f * 128.f); ch = u >> 4; chunk = u & 15; lgn1 = 8; base = 64; }
    else if (u < 512) { int w = u - 256; V = V02; Pp = P2p; nsp = 4; A1b = X0; n1 = 256; n2 = 64; s = 4; inv = 1.f / (64.f * 64.f); ch = w >> 4; chunk = w & 15; lgn1 = 8; base = 128; }
    else              { int w = u - 512; V = V12; Pp = P2p; nsp = 4; A1b = X1; n1 = 128; n2 = 64; s = 2; inv = 1.f / (64.f * 64.f); ch = w >> 3; chunk = w & 7; lgn1 = 7; base = 256; }
    int mask = n1 - 1;
    for (int i = t; i < n1; i += 256) sRl[i] = rtab_val(n1, n2, i);
    int mxg = chunk * 16;
    b = ch >> 3; l2 = ch & 7;
    const float* vch = V + (size_t)ch * n2 * n1;
    float Pv = 0.f;
    for (int i = 0; i < nsp; ++i) Pv += Pp[ch * nsp + i];
    float a = PI_F / (float)s;
    int per = 2 * s;
    // ---- phase A: U rows [mxg-2, mxg+17) -> Us[0..19)
    if (n1 == 256) {
      int cid = t & 63;
      float4 acc[5];
#pragma unroll
      for (int j = 0; j < 5; ++j) acc[j] = make_float4(0.f, 0.f, 0.f, 0.f);
      for (int nx0 = 0; nx0 < n2; nx0 += 16) {
        __syncthreads();
        const float4* s4 = (const float4*)(vch + (size_t)nx0 * 256);
        for (int i = t; i < 1024; i += 256) ((float4*)eBuf)[i] = s4[i];
        __syncthreads();
#pragma unroll
        for (int k = 0; k < 16; ++k) {
          int nx = nx0 + k;
          float4 vv = *(const float4*)&eBuf[k * 256 + 4 * cid];
#pragma unroll
          for (int j = 0; j < 5; ++j) {
            int mx = (mxg - 2 + wv + 4 * j) & mask;
            float rv = sRl[(mx - s * nx) & mask];
            acc[j].x += rv * vv.x; acc[j].y += rv * vv.y;
            acc[j].z += rv * vv.z; acc[j].w += rv * vv.w;
          }
        }
      }
      float smy[4];
#pragma unroll
      for (int j = 0; j < 4; ++j) smy[j] = sinf(a * (float)((4 * cid + j) & (per - 1)));
#pragma unroll
      for (int j = 0; j < 5; ++j) {
        int rl = wv + 4 * j;
        if (rl < 19) {
          int mx = (mxg - 2 + rl) & mask;
          float q = inv * sinf(a * (float)(mx & (per - 1))) * Pv;
          float4 o = acc[j];
          o.x -= q * smy[0]; o.y -= q * smy[1]; o.z -= q * smy[2]; o.w -= q * smy[3];
          *(float4*)&Us[rl * 256 + 4 * cid] = o;
        }
      }
    } else {
      // n1 = 128 (p12)
      int cid = t & 31;
      int owner = t >> 5;  // 0..7
      float4 acc[3];
#pragma unroll
      for (int j = 0; j < 3; ++j) acc[j] = make_float4(0.f, 0.f, 0.f, 0.f);
      for (int nx0 = 0; nx0 < 64; nx0 += 16) {
        __syncthreads();
        const float4* s4 = (const float4*)(vch + (size_t)nx0 * 128);
        for (int i = t; i < 512; i += 256) ((float4*)eBuf)[i] = s4[i];
        __syncthreads();
#pragma unroll
        for (int k = 0; k < 16; ++k) {
          int nx = nx0 + k;
          float4 vv = *(const float4*)&eBuf[k * 128 + 4 * cid];
#pragma unroll
          for (int j = 0; j < 3; ++j) {
            int mx = (mxg - 2 + owner + 8 * j) & 127;
            float rv = sRl[(mx - 2 * nx) & 127];
            acc[j].x += rv * vv.x; acc[j].y += rv * vv.y;
            acc[j].z += rv * vv.z; acc[j].w += rv * vv.w;
          }
        }
      }
      float smy[4];
#pragma unroll
      for (int j = 0; j < 4; ++j) smy[j] = sinf(a * (float)((4 * cid + j) & 3));
#pragma unroll
      for (int j = 0; j < 3; ++j) {
        int rl = owner + 8 * j;
        if (rl < 19) {
          int mx = (mxg - 2 + rl) & 127;
          float q = inv * sinf(a * (float)(mx & 3)) * Pv;
          float4 o = acc[j];
          o.x -= q * smy[0]; o.y -= q * smy[1]; o.z -= q * smy[2]; o.w -= q * smy[3];
          *(float4*)&Us[rl * 128 + 4 * cid] = o;
        }
      }
    }
    __syncthreads();
    // ---- phase B: corr of A1 rows [mxg, mxg+16) against Us (LDS)
    int lgtpr = lgn1 - 2;
    int tpr = 1 << lgtpr;
    int rif = 256 >> lgtpr;
    int rid = t >> lgtpr;
    int cid2 = t & (tpr - 1);
    int ty = cid2 * 4;
    int tym = (ty - 4) & mask;
    int n1sq = n1 * n1;
    const float* A1 = A1b + (size_t)(b * 8) * n1sq;
    for (int rr = 0; rr < 16; rr += rif) {
      int ri = rr + rid;  // 0..15
      const float* r0 = &Us[(ri + 2) * n1];
      const float* r1 = &Us[(ri + 1) * n1];
      const float* r2 = &Us[ri * n1];
      const float* r3 = &Us[(ri + 3) * n1];
      float4 a0 = *(const float4*)(r0 + tym);
      float4 b0 = *(const float4*)(r0 + ty);
      float4 a1 = *(const float4*)(r1 + tym);
      float4 b1 = *(const float4*)(r1 + ty);
      float4 b2 = *(const float4*)(r2 + ty);
      float4 a3 = *(const float4*)(r3 + tym);
      float4 b3 = *(const float4*)(r3 + ty);
      const float* rA = A1 + (size_t)(mxg + ri) * n1 + ty;
#pragma unroll
      for (int l1 = 0; l1 < 8; ++l1) {
        float4 xv = *(const float4*)(rA + (size_t)l1 * n1sq);
        accC[l1][0] += xv.x * b0.x + xv.y * b0.y + xv.z * b0.z + xv.w * b0.w;
        accC[l1][1] += xv.x * a0.w + xv.y * b0.x + xv.z * b0.y + xv.w * b0.z;
        accC[l1][2] += xv.x * a0.z + xv.y * a0.w + xv.z * b0.x + xv.w * b0.y;
        accC[l1][3] += xv.x * b1.x + xv.y * b1.y + xv.z * b1.z + xv.w * b1.w;
        accC[l1][4] += xv.x * a1.w + xv.y * b1.x + xv.z * b1.y + xv.w * b1.z;
        accC[l1][5] += xv.x * b2.x + xv.y * b2.y + xv.z * b2.z + xv.w * b2.w;
        accC[l1][6] += xv.x * a3.w + xv.y * b3.x + xv.z * b3.y + xv.w * b3.z;
      }
    }
  } else {
    // ================= self-corr (groups 0,3,5) =================
    int w = u - 640;
    const float* Ab; int loc, lgn1, lgc;
    if (w < 256)      { loc = w;       Ab = X0; lgn1 = 8; lgc = 4; base = 0;   }
    else if (w < 384) { loc = w - 256; Ab = X1; lgn1 = 7; lgc = 3; base = 192; }
    else              { loc = w - 384; Ab = X2; lgn1 = 6; lgc = 2; base = 320; }
    int n1 = 1 << lgn1;
    int mask = n1 - 1;
    int n1sq = n1 * n1;
    int chunk = loc & ((1 << lgc) - 1);
    int bl2 = loc >> lgc;
    b = bl2 >> 3; l2 = bl2 & 7;
    const float* A1 = Ab + (size_t)(b * 8) * n1sq;
    const float* A2 = Ab + (size_t)(b * 8 + l2) * n1sq;
    int lgtpr = lgn1 - 2;
    int tpr = 1 << lgtpr;
    int rif = 256 >> lgtpr;
    int rid = t >> lgtpr;
    int cid2 = t & (tpr - 1);
    int ty = cid2 * 4;
    int tym = (ty - 4) & mask;
    for (int rr = 0; rr < 16; rr += rif) {
      int row = chunk * 16 + rr + rid;
      const float* r0 = A2 + (size_t)row * n1;
      const float* r1 = A2 + (size_t)((row - 1) & mask) * n1;
      const float* r2 = A2 + (size_t)((row - 2) & mask) * n1;
      const float* r3 = A2 + (size_t)((row + 1) & mask) * n1;
      float4 a0 = *(const float4*)(r0 + tym);
      float4 b0 = *(const float4*)(r0 + ty);
      float4 a1 = *(const float4*)(r1 + tym);
      float4 b1 = *(const float4*)(r1 + ty);
      float4 b2 = *(const float4*)(r2 + ty);
      float4 a3 = *(const float4*)(r3 + tym);
      float4 b3 = *(const float4*)(r3 + ty);
      const float* rA = A1 + (size_t)row * n1 + ty;
#pragma unroll
      for (int l1 = 0; l1 < 8; ++l1) {
        float4 xv = *(const float4*)(rA + (size_t)l1 * n1sq);
        accC[l1][0] += xv.x * b0.x + xv.y * b0.y + xv.z * b0.z + xv.w * b0.w;
        accC[l1][1] += xv.x * a0.w + xv.y * b0.x + xv.z * b0.y + xv.w * b0.z;
        accC[l1][2] += xv.x * a0.z + xv.y * a0.w + xv.z * b0.x + xv.w * b0.y;
        accC[l1][3] += xv.x * b1.x + xv.y * b1.y + xv.z * b1.z + xv.w * b1.w;
        accC[l1][4] += xv.x * a1.w + xv.y * b1.x + xv.z * b1.y + xv.w * b1.z;
        accC[l1][5] += xv.x * b2.x + xv.y * b2.y + xv.z * b2.z + xv.w * b2.w;
        accC[l1][6] += xv.x * a3.w + xv.y * b3.x + xv.z * b3.y + xv.w * b3.z;
      }
    }
  }
  // ---- shared epilogue: 2-shfl fold + LDS transpose (stride 60) ----
  float* af = &accC[0][0];
#pragma unroll
  for (int j = 0; j < 56; ++j) {
    float v = af[j];
    v += __shfl_down(v, 32, 64);
    v += __shfl_down(v, 16, 64);
    af[j] = v;
  }
  if (lane < 16) {
    float* rowp = eBuf + (wv * 16 + lane) * 60;
#pragma unroll
    for (int j = 0; j < 14; ++j)
      *(float4*)&rowp[4 * j] =
          make_float4(af[4 * j], af[4 * j + 1], af[4 * j + 2], af[4 * j + 3]);
  }
  __syncthreads();
  if (t < 224) {
    int v = t >> 2, q = t & 3;
    float s2 = 0.f;
#pragma unroll
    for (int i = 0; i < 16; ++i) s2 += eBuf[(q * 16 + i) * 60 + v];
    s2 += __shfl_down(s2, 2, 64);
    s2 += __shfl_down(s2, 1, 64);
    if (q == 0) {
      int l1o = v / 7, p = v % 7;
      atomicAdd(&out[((size_t)b * 384 + base + l1o * 8 + l2) * 7 + p], s2);
    }
  }
}

extern "C" void kernel_launch(void* const* d_in, const int* in_sizes, int n_in,
                              void* d_out, int out_size, void* d_ws, size_t ws_size,
                              hipStream_t stream) {
  const float* X0 = (const float*)d_in[0];  // [2,8,256,256]
  const float* X1 = (const float*)d_in[1];  // [2,8,128,128]
  const float* X2 = (const float*)d_in[2];  // [2,8,64,64]
  float* out = (float*)d_out;               // [2,384,7]
  float* ws = (float*)d_ws;

  float* V01 = ws + 2359296;
  float* V02 = ws + 2883584;
  float* V12 = ws + 3145728;
  float* P1p = ws + 3276800;
  float* P2p = ws + 3276928;

  k_front<<<449, 256, 0, stream>>>(X1, X2, P1p, P2p, V01, V02, V12, out);
  k_main<<<1088, 256, 0, stream>>>(X0, X1, X2, V01, V02, V12, P1p, P2p, out);
}